// Round 16
// baseline (2899.151 us; speedup 1.0000x reference)
//
#include <hip/hip_runtime.h>
#include <hip/hip_bf16.h>

// Problem: N=4096 nodes, T=64, V=30000, H=256, L=2 layers, gates=4H=1024
#define TT 64
#define HH 256
#define GG 1024

typedef _Float16 f16;
typedef __attribute__((ext_vector_type(8))) _Float16 f16x8;
typedef __attribute__((ext_vector_type(4))) _Float16 f16x4;
typedef __attribute__((ext_vector_type(4))) float f32x4;

// fast activations via v_exp_f32 (2^x) + v_rcp_f32 (validated r5-r15: absmax 1.22e-4).
__device__ __forceinline__ float exp2_(float x) { return __builtin_amdgcn_exp2f(x); }
__device__ __forceinline__ float sig_(float x) {
    return __builtin_amdgcn_rcpf(1.0f + exp2_(-1.44269504f * x));
}
__device__ __forceinline__ float tanh_(float x) {
    return 1.0f - 2.0f * __builtin_amdgcn_rcpf(1.0f + exp2_(2.88539008f * x));
}
// precise forms for the fallback path
__device__ __forceinline__ float sigp_(float x) { return 1.0f / (1.0f + __expf(-x)); }
__device__ __forceinline__ float tanhp_(float x) {
    x = fminf(fmaxf(x, -15.0f), 15.0f);
    float e = __expf(-2.0f * x);
    return (1.0f - e) / (1.0f + e);
}

// ==================== weight packing (B-fragment order) ====================
// Wp[l][kk][nt][lane][j] = Wcat_l[kk*32 + 8*(lane>>4) + j][nt*16 + (lane&15)]
// Wcat_l = concat_K(Wx[l] (k<256), Wh[l] (k>=256))  -> [512][1024]
__global__ void pack_weights(const float* __restrict__ Wx, const float* __restrict__ Wh,
                             f16* __restrict__ Wp) {
    int t = blockIdx.x * 256 + threadIdx.x;   // 131072 items
    int lane = t & 63;
    int nt = (t >> 6) & 63;
    int kk = (t >> 12) & 15;
    int l = t >> 16;
    int n = nt * 16 + (lane & 15);
    int kbase = kk * 32 + 8 * (lane >> 4);
    const float* src = (kbase < 256) ? (Wx + (size_t)l * HH * GG + (size_t)kbase * GG + n)
                                     : (Wh + (size_t)l * HH * GG + (size_t)(kbase - 256) * GG + n);
    f16x8 v;
#pragma unroll
    for (int j = 0; j < 8; ++j) v[j] = (f16)src[(size_t)j * GG];
    *(f16x8*)(Wp + (size_t)t * 8) = v;
}

// ==================== embW2 = embed @ Wx0 + b0, CONSUMER-FRAGMENT layout ====================
// embW2[row][cw(8)][arow(16)][ctt(8)] f16; consumer col = (ctt>>1)*256 + cw*32 +
// (ctt&1)*16 + arow. Bijection from producer col nt*16+arow: cw=(nt>>1)&7,
// ctt=((nt>>4)<<1)|(nt&1).
__global__ __launch_bounds__(512) void embw_gemm(
    const float* __restrict__ embed, const float* __restrict__ bias,
    const f16* __restrict__ Wp, f16* __restrict__ embW, int vocab)
{
    __shared__ f16 a_lds[32 * HH];   // 16KB, XOR-swizzled rows
    const int tid = threadIdx.x;
    const int lane = tid & 63;
    const int w = tid >> 6;          // 0..7
    const int arow = lane & 15;
    const int g4 = lane >> 4;
    const int r0 = blockIdx.x * 32;

#pragma unroll
    for (int i = 0; i < 4; ++i) {
        int chunk = tid + i * 512;
        int row = chunk >> 6;
        int c4 = chunk & 63;
        int grow = r0 + row; if (grow >= vocab) grow = vocab - 1;
        float4 v = *(const float4*)(embed + (size_t)grow * HH + c4 * 4);
        int idx = row * HH + ((c4 * 4) ^ ((row & 7) << 3));
        *(f16x4*)&a_lds[idx] = (f16x4){(f16)v.x, (f16)v.y, (f16)v.z, (f16)v.w};
    }
    __syncthreads();

    float breg[8];
#pragma unroll
    for (int tt = 0; tt < 8; ++tt) breg[tt] = bias[(w * 8 + tt) * 16 + arow];

    f32x4 acc[2][8];
#pragma unroll
    for (int mt = 0; mt < 2; ++mt)
#pragma unroll
        for (int tt = 0; tt < 8; ++tt)
            acc[mt][tt] = (f32x4){breg[tt], breg[tt], breg[tt], breg[tt]};

    const f16* wl = Wp + (size_t)lane * 8;
#pragma unroll 2
    for (int kk = 0; kk < 8; ++kk) {
        int sw = (kk * 32 + g4 * 8) ^ ((arow & 7) << 3);
        f16x8 a0 = *(const f16x8*)&a_lds[arow * HH + sw];
        f16x8 a1 = *(const f16x8*)&a_lds[(arow + 16) * HH + sw];
        const f16* wkk = wl + (size_t)kk * 64 * 64 * 8;
#pragma unroll
        for (int tt = 0; tt < 8; ++tt) {
            f16x8 b = *(const f16x8*)(wkk + (size_t)(w * 8 + tt) * 64 * 8);
            acc[0][tt] = __builtin_amdgcn_mfma_f32_16x16x32_f16(a0, b, acc[0][tt], 0, 0, 0);
            acc[1][tt] = __builtin_amdgcn_mfma_f32_16x16x32_f16(a1, b, acc[1][tt], 0, 0, 0);
        }
    }

#pragma unroll
    for (int mt = 0; mt < 2; ++mt)
#pragma unroll
        for (int tt = 0; tt < 8; ++tt) {
            int nt = w * 8 + tt;
            int cw = (nt >> 1) & 7;
            int ctt = ((nt >> 4) << 1) | (nt & 1);
#pragma unroll
            for (int r = 0; r < 4; ++r) {
                int row = r0 + mt * 16 + g4 * 4 + r;
                if (row < vocab)
                    embW[(size_t)row * GG + cw * 128 + arow * 8 + ctt] = (f16)acc[mt][tt][r];
            }
        }
}

// ==================== recurrent kernel ====================
// 128 blocks x 512 threads, NB=32. r15 base (1 barrier/step, deferred zx add,
// h0+h1 double-buffered) + depth-1 B-fragment double-buffer on both kk loops.
// KEY EXPERIMENT: amdgpu_waves_per_eu(2,2) instead of __launch_bounds__ --
// the block is structurally 2 waves/SIMD (8 waves / 4 SIMDs), so targeting
// exactly 2 waves/EU legitimately unlocks the 256-VGPR allocation that the
// default 4-wave target clamped to 128 (the r5/r6/r7/r9/r12 spill wall).
// Named bq0/bq1 arrays with literal parity bodies only (rule #20).
#define NB2 32
#define LDH 264    // h row stride (256 + 8 f16 pad)

__global__ __attribute__((amdgpu_flat_work_group_size(512, 512), amdgpu_waves_per_eu(2, 2)))
void lstm_rec2(
    const int* __restrict__ data, const float* __restrict__ bias,
    const f16* __restrict__ embW, const f16* __restrict__ Wp,
    float* __restrict__ out)
{
    __shared__ f16 h0s[2][NB2 * LDH];  // 33.8KB double-buffered
    __shared__ f16 h1s[2][NB2 * LDH];  // 33.8KB double-buffered
    __shared__ int toks[NB2 * TT];     // 8KB

    const int tid = threadIdx.x;
    const int lane = tid & 63;
    const int w = tid >> 6;          // 0..7
    const int arow = lane & 15;
    const int g4 = lane >> 4;
    const int n0 = blockIdx.x * NB2;

    for (int i = tid; i < NB2 * LDH; i += 512) {
        h0s[0][i] = (f16)0; h0s[1][i] = (f16)0;
        h1s[0][i] = (f16)0; h1s[1][i] = (f16)0;
    }
    for (int i = tid; i < NB2 * TT; i += 512) toks[i] = data[n0 * TT + i];

    float breg1[8];
#pragma unroll
    for (int tt = 0; tt < 8; ++tt) {
        int col = (tt >> 1) * 256 + w * 32 + (tt & 1) * 16 + arow;
        breg1[tt] = bias[GG + col];
    }

    float c0[16], c1[16];
#pragma unroll
    for (int i = 0; i < 16; ++i) { c0[i] = 0.0f; c1[i] = 0.0f; }

    const f16* wl0 = Wp + (size_t)8 * 32768 + (size_t)lane * 8;   // l0 Wh (kk 8..15)
    const f16* wl1 = Wp + (size_t)16 * 32768 + (size_t)lane * 8;  // l1 (kk 0..15)
    const int zoff = w * 128 + arow * 8;   // embW2 fragment sub-offset

    int cur0 = 0, cur1 = 0;

    __syncthreads();

#pragma unroll 1
    for (int t = 0; t < TT; ++t) {
        // ---- issue zx fragment gathers (NOT consumed until after L0h) ----
        f16x8 zfa0, zfa1, zfa2, zfa3, zfb0, zfb1, zfb2, zfb3;
        {
            int nb = g4 * 4;
            int t0 = toks[(nb + 0) * TT + t];
            int t1 = toks[(nb + 1) * TT + t];
            int t2 = toks[(nb + 2) * TT + t];
            int t3 = toks[(nb + 3) * TT + t];
            zfa0 = *(const f16x8*)(embW + (size_t)t0 * GG + zoff);
            zfa1 = *(const f16x8*)(embW + (size_t)t1 * GG + zoff);
            zfa2 = *(const f16x8*)(embW + (size_t)t2 * GG + zoff);
            zfa3 = *(const f16x8*)(embW + (size_t)t3 * GG + zoff);
        }
        {
            int nb = 16 + g4 * 4;
            int t0 = toks[(nb + 0) * TT + t];
            int t1 = toks[(nb + 1) * TT + t];
            int t2 = toks[(nb + 2) * TT + t];
            int t3 = toks[(nb + 3) * TT + t];
            zfb0 = *(const f16x8*)(embW + (size_t)t0 * GG + zoff);
            zfb1 = *(const f16x8*)(embW + (size_t)t1 * GG + zoff);
            zfb2 = *(const f16x8*)(embW + (size_t)t2 * GG + zoff);
            zfb3 = *(const f16x8*)(embW + (size_t)t3 * GG + zoff);
        }

        // ---- L0 h-part: h0[cur0] @ Wh0, depth-1 B dbuf, acc starts at ZERO ----
        f32x4 acc[2][8];
#pragma unroll
        for (int mt = 0; mt < 2; ++mt)
#pragma unroll
            for (int tt = 0; tt < 8; ++tt)
                acc[mt][tt] = (f32x4){0.0f, 0.0f, 0.0f, 0.0f};

        const f16* h0cur = h0s[cur0];
        {
            f16x8 bq0[8], bq1[8];
#pragma unroll
            for (int j = 0; j < 8; ++j)
                bq0[j] = *(const f16x8*)(wl0 + (size_t)((j >> 1) * 16 + w * 2 + (j & 1)) * 512);
#pragma unroll
            for (int kp = 0; kp < 4; ++kp) {
                const int kk = kp * 2;
#pragma unroll
                for (int j = 0; j < 8; ++j)
                    bq1[j] = *(const f16x8*)(wl0 + (size_t)(kk + 1) * 32768 +
                                             (size_t)((j >> 1) * 16 + w * 2 + (j & 1)) * 512);
                {
                    int k0 = kk * 32 + 8 * g4;
                    f16x8 a0 = *(const f16x8*)&h0cur[arow * LDH + k0];
                    f16x8 a1 = *(const f16x8*)&h0cur[(arow + 16) * LDH + k0];
#pragma unroll
                    for (int tt = 0; tt < 8; ++tt) {
                        acc[0][tt] = __builtin_amdgcn_mfma_f32_16x16x32_f16(a0, bq0[tt], acc[0][tt], 0, 0, 0);
                        acc[1][tt] = __builtin_amdgcn_mfma_f32_16x16x32_f16(a1, bq0[tt], acc[1][tt], 0, 0, 0);
                    }
                }
                if (kp < 3) {
#pragma unroll
                    for (int j = 0; j < 8; ++j)
                        bq0[j] = *(const f16x8*)(wl0 + (size_t)(kk + 2) * 32768 +
                                                 (size_t)((j >> 1) * 16 + w * 2 + (j & 1)) * 512);
                }
                {
                    int k0 = (kk + 1) * 32 + 8 * g4;
                    f16x8 a0 = *(const f16x8*)&h0cur[arow * LDH + k0];
                    f16x8 a1 = *(const f16x8*)&h0cur[(arow + 16) * LDH + k0];
#pragma unroll
                    for (int tt = 0; tt < 8; ++tt) {
                        acc[0][tt] = __builtin_amdgcn_mfma_f32_16x16x32_f16(a0, bq1[tt], acc[0][tt], 0, 0, 0);
                        acc[1][tt] = __builtin_amdgcn_mfma_f32_16x16x32_f16(a1, bq1[tt], acc[1][tt], 0, 0, 0);
                    }
                }
            }
        }

        // ---- deferred add: acc += zx (= x@Wx0 + b0); gathers have drained ----
#pragma unroll
        for (int tt = 0; tt < 8; ++tt) {
            acc[0][tt][0] += (float)zfa0[tt];
            acc[0][tt][1] += (float)zfa1[tt];
            acc[0][tt][2] += (float)zfa2[tt];
            acc[0][tt][3] += (float)zfa3[tt];
            acc[1][tt][0] += (float)zfb0[tt];
            acc[1][tt][1] += (float)zfb1[tt];
            acc[1][tt][2] += (float)zfb2[tt];
            acc[1][tt][3] += (float)zfb3[tt];
        }

        // ---- L0 gates -> h0[cur0^1] (no barrier: different buffer) ----
        f16* h0new = h0s[cur0 ^ 1];
#pragma unroll
        for (int mt = 0; mt < 2; ++mt)
#pragma unroll
            for (int sub = 0; sub < 2; ++sub)
#pragma unroll
                for (int r = 0; r < 4; ++r) {
                    int node = mt * 16 + g4 * 4 + r;
                    float i_ = sig_(acc[mt][0 + sub][r]);
                    float f_ = sig_(acc[mt][2 + sub][r]);
                    float g_ = tanh_(acc[mt][4 + sub][r]);
                    float o_ = sig_(acc[mt][6 + sub][r]);
                    int ci = mt * 8 + sub * 4 + r;
                    float c = fmaf(f_, c0[ci], i_ * g_);
                    c0[ci] = c;
                    int u = w * 32 + sub * 16 + arow;
                    h0new[node * LDH + u] = (f16)(o_ * tanh_(c));
                }
        __syncthreads();   // THE barrier: h0new visible to all waves for L1

        // ---- L1: [h0_new | h1_prev] @ [Wx1; Wh1], depth-1 B dbuf ----
        f32x4 acc1[2][8];
#pragma unroll
        for (int mt = 0; mt < 2; ++mt)
#pragma unroll
            for (int tt = 0; tt < 8; ++tt)
                acc1[mt][tt] = (f32x4){breg1[tt], breg1[tt], breg1[tt], breg1[tt]};

        const f16* h1cur = h1s[cur1];
        {
            f16x8 cq0[8], cq1[8];
#pragma unroll
            for (int j = 0; j < 8; ++j)
                cq0[j] = *(const f16x8*)(wl1 + (size_t)((j >> 1) * 16 + w * 2 + (j & 1)) * 512);
#pragma unroll
            for (int kp = 0; kp < 8; ++kp) {
                const int kk = kp * 2;
                const f16* asrcE = (kk < 8) ? (const f16*)h0new : h1cur;
                const f16* asrcO = (kk + 1 < 8) ? (const f16*)h0new : h1cur;
#pragma unroll
                for (int j = 0; j < 8; ++j)
                    cq1[j] = *(const f16x8*)(wl1 + (size_t)(kk + 1) * 32768 +
                                             (size_t)((j >> 1) * 16 + w * 2 + (j & 1)) * 512);
                {
                    int k0 = (kk & 7) * 32 + 8 * g4;
                    f16x8 a0 = *(const f16x8*)&asrcE[arow * LDH + k0];
                    f16x8 a1 = *(const f16x8*)&asrcE[(arow + 16) * LDH + k0];
#pragma unroll
                    for (int tt = 0; tt < 8; ++tt) {
                        acc1[0][tt] = __builtin_amdgcn_mfma_f32_16x16x32_f16(a0, cq0[tt], acc1[0][tt], 0, 0, 0);
                        acc1[1][tt] = __builtin_amdgcn_mfma_f32_16x16x32_f16(a1, cq0[tt], acc1[1][tt], 0, 0, 0);
                    }
                }
                if (kp < 7) {
#pragma unroll
                    for (int j = 0; j < 8; ++j)
                        cq0[j] = *(const f16x8*)(wl1 + (size_t)(kk + 2) * 32768 +
                                                 (size_t)((j >> 1) * 16 + w * 2 + (j & 1)) * 512);
                }
                {
                    int k0 = ((kk + 1) & 7) * 32 + 8 * g4;
                    f16x8 a0 = *(const f16x8*)&asrcO[arow * LDH + k0];
                    f16x8 a1 = *(const f16x8*)&asrcO[(arow + 16) * LDH + k0];
#pragma unroll
                    for (int tt = 0; tt < 8; ++tt) {
                        acc1[0][tt] = __builtin_amdgcn_mfma_f32_16x16x32_f16(a0, cq1[tt], acc1[0][tt], 0, 0, 0);
                        acc1[1][tt] = __builtin_amdgcn_mfma_f32_16x16x32_f16(a1, cq1[tt], acc1[1][tt], 0, 0, 0);
                    }
                }
            }
        }

        // ---- L1 gates -> h1[cur1^1] (no barrier: dbuf) ----
#pragma unroll
        for (int mt = 0; mt < 2; ++mt)
#pragma unroll
            for (int sub = 0; sub < 2; ++sub)
#pragma unroll
                for (int r = 0; r < 4; ++r) {
                    int node = mt * 16 + g4 * 4 + r;
                    float i_ = sig_(acc1[mt][0 + sub][r]);
                    float f_ = sig_(acc1[mt][2 + sub][r]);
                    float g_ = tanh_(acc1[mt][4 + sub][r]);
                    float o_ = sig_(acc1[mt][6 + sub][r]);
                    int ci = mt * 8 + sub * 4 + r;
                    float c = fmaf(f_, c1[ci], i_ * g_);
                    c1[ci] = c;
                    int u = w * 32 + sub * 16 + arow;
                    h1s[cur1 ^ 1][node * LDH + u] = (f16)(o_ * tanh_(c));
                }
        cur0 ^= 1;
        cur1 ^= 1;
    }
    __syncthreads();

    for (int i = tid; i < NB2 * HH; i += 512) {
        int n = i >> 8, k = i & 255;
        out[(size_t)(n0 + n) * HH + k] = (float)h1s[cur1][n * LDH + k];
    }
}

// ==================== fallback: round-2 MFMA path ====================
__global__ void convert_embed(const float* __restrict__ e, f16* __restrict__ o, int n8) {
    int i = blockIdx.x * 256 + threadIdx.x;
    if (i >= n8) return;
    size_t p = (size_t)i * 8;
    float4 a = *(const float4*)(e + p);
    float4 b = *(const float4*)(e + p + 4);
    f16x8 v = { (f16)a.x, (f16)a.y, (f16)a.z, (f16)a.w,
                (f16)b.x, (f16)b.y, (f16)b.z, (f16)b.w };
    *(f16x8*)(o + p) = v;
}

#define FB 32
#define FTH 512
#define FLD 264
__device__ __forceinline__ void fb_layer_step(
    const f16 (*bx)[FLD], f16 (*bh)[FLD], const f16* __restrict__ wlayer,
    const float* breg_l, float* c_l, int lane, int w)
{
    f32x4 acc[2][8];
#pragma unroll
    for (int mt = 0; mt < 2; ++mt)
#pragma unroll
        for (int tt = 0; tt < 8; ++tt) {
            float b = breg_l[tt];
            acc[mt][tt] = (f32x4){b, b, b, b};
        }
    const int arow = lane & 15;
    const int koff = 8 * (lane >> 4);
    const f16* wl = wlayer + (size_t)lane * 8;
#pragma unroll 2
    for (int kk = 0; kk < 16; ++kk) {
        int k0 = (kk & 7) * 32 + koff;
        const f16(*src)[FLD] = (kk < 8) ? bx : (const f16(*)[FLD])bh;
        f16x8 a0 = *(const f16x8*)&src[arow][k0];
        f16x8 a1 = *(const f16x8*)&src[arow + 16][k0];
        const f16* wkk = wl + (size_t)kk * 64 * 64 * 8;
#pragma unroll
        for (int tt = 0; tt < 8; ++tt) {
            int nt = (tt >> 1) * 16 + w * 2 + (tt & 1);
            f16x8 b = *(const f16x8*)(wkk + (size_t)nt * 64 * 8);
            acc[0][tt] = __builtin_amdgcn_mfma_f32_16x16x32_f16(a0, b, acc[0][tt], 0, 0, 0);
            acc[1][tt] = __builtin_amdgcn_mfma_f32_16x16x32_f16(a1, b, acc[1][tt], 0, 0, 0);
        }
    }
    __syncthreads();
#pragma unroll
    for (int mt = 0; mt < 2; ++mt)
#pragma unroll
        for (int sub = 0; sub < 2; ++sub) {
            f32x4 iv = acc[mt][0 + sub], fv = acc[mt][2 + sub];
            f32x4 gv = acc[mt][4 + sub], ov = acc[mt][6 + sub];
#pragma unroll
            for (int r = 0; r < 4; ++r) {
                float i_ = sigp_(iv[r]), f_ = sigp_(fv[r]), g_ = tanhp_(gv[r]), o_ = sigp_(ov[r]);
                int ci = mt * 8 + sub * 4 + r;
                float c = fmaf(f_, c_l[ci], i_ * g_);
                c_l[ci] = c;
                int node = mt * 16 + (lane >> 4) * 4 + r;
                int unit = w * 32 + sub * 16 + (lane & 15);
                bh[node][unit] = (f16)(o_ * tanhp_(c));
            }
        }
    __syncthreads();
}

__global__ __launch_bounds__(FTH, 2) void lstm_mfma_fb(
    const int* __restrict__ data, const float* __restrict__ bias,
    const f16* __restrict__ emb, const f16* __restrict__ Wp,
    float* __restrict__ out, int vocab)
{
    __shared__ f16 x_lds[FB][FLD];
    __shared__ f16 h0_lds[FB][FLD];
    __shared__ f16 h1_lds[FB][FLD];
    const int tid = threadIdx.x;
    const int lane = tid & 63;
    const int w = tid >> 6;
    const int n0 = blockIdx.x * FB;
    for (int i = tid; i < FB * FLD; i += FTH) {
        (&h0_lds[0][0])[i] = (f16)0.0f; (&h1_lds[0][0])[i] = (f16)0.0f;
    }
    float breg[2][8];
#pragma unroll
    for (int l = 0; l < 2; ++l)
#pragma unroll
        for (int tt = 0; tt < 8; ++tt) {
            int col = (tt >> 1) * 256 + w * 32 + (tt & 1) * 16 + (lane & 15);
            breg[l][tt] = bias[l * GG + col];
        }
    float cst[2][16];
#pragma unroll
    for (int i = 0; i < 32; ++i) (&cst[0][0])[i] = 0.0f;
    __syncthreads();
    const f16* Wp0 = Wp;
    const f16* Wp1 = Wp + (size_t)16 * 64 * 64 * 8;
    for (int t = 0; t < TT; ++t) {
        {
            int n = tid >> 4;
            int cg = (tid & 15) * 16;
            int row = data[(n0 + n) * TT + t];
            row = min(max(row, 0), vocab - 1);
            const f16* src = emb + (size_t)row * HH + cg;
            *(f16x8*)&x_lds[n][cg] = *(const f16x8*)src;
            *(f16x8*)&x_lds[n][cg + 8] = *(const f16x8*)(src + 8);
        }
        __syncthreads();
        fb_layer_step(x_lds, h0_lds, Wp0, breg[0], cst[0], lane, w);
        fb_layer_step((const f16(*)[FLD])h0_lds, h1_lds, Wp1, breg[1], cst[1], lane, w);
    }
    for (int i = tid; i < FB * HH; i += FTH) {
        int n = i >> 8, k = i & 255;
        out[(size_t)(n0 + n) * HH + k] = (float)h1_lds[n][k];
    }
}

// ==================== launcher ====================
extern "C" void kernel_launch(void* const* d_in, const int* in_sizes, int n_in,
                              void* d_out, int out_size, void* d_ws, size_t ws_size,
                              hipStream_t stream) {
    const int* data = (const int*)d_in[0];
    const float* embed = (const float*)d_in[1];
    const float* Wx = (const float*)d_in[2];
    const float* Wh = (const float*)d_in[3];
    const float* bias = (const float*)d_in[4];
    float* out = (float*)d_out;
    const int vocab = in_sizes[1] / HH;       // 30000
    const int nNodes = in_sizes[0] / TT;      // 4096

    const size_t wp_bytes = (size_t)2 * 16 * 64 * 64 * 8 * 2;   // 2 MB
    const size_t embw_bytes = (size_t)vocab * GG * 2;           // 61.4 MB
    const size_t emb16_bytes = (size_t)vocab * HH * 2;          // 15.4 MB

    if (ws_size >= embw_bytes + wp_bytes) {
        f16* embW = (f16*)d_ws;
        f16* Wp = (f16*)((char*)d_ws + embw_bytes);
        pack_weights<<<dim3(512), dim3(256), 0, stream>>>(Wx, Wh, Wp);
        embw_gemm<<<dim3((vocab + 31) / 32), dim3(512), 0, stream>>>(embed, bias, Wp, embW, vocab);
        lstm_rec2<<<dim3(nNodes / NB2), dim3(512), 0, stream>>>(data, bias, embW, Wp, out);
        return;
    }
    // fallback: fp16 embed table + packed weights (r2 path)
    f16* emb_h = (f16*)d_ws;
    f16* Wp = (f16*)((char*)d_ws + emb16_bytes);
    int n8 = in_sizes[1] / 8;
    convert_embed<<<dim3((n8 + 255) / 256), dim3(256), 0, stream>>>(embed, emb_h, n8);
    pack_weights<<<dim3(512), dim3(256), 0, stream>>>(Wx, Wh, Wp);
    lstm_mfma_fb<<<dim3(nNodes / FB), dim3(FTH), 0, stream>>>(data, bias, emb_h, Wp, out, vocab);
}

// Round 17
// 2217.256 us; speedup vs baseline: 1.3075x; 1.3075x over previous
//
#include <hip/hip_runtime.h>
#include <hip/hip_bf16.h>

// Problem: N=4096 nodes, T=64, V=30000, H=256, L=2 layers, gates=4H=1024
#define TT 64
#define HH 256
#define GG 1024

typedef _Float16 f16;
typedef __attribute__((ext_vector_type(8))) _Float16 f16x8;
typedef __attribute__((ext_vector_type(4))) _Float16 f16x4;
typedef __attribute__((ext_vector_type(4))) float f32x4;

// fast activations via v_exp_f32 (2^x) + v_rcp_f32 (validated r5-r16: absmax 1.22e-4).
__device__ __forceinline__ float exp2_(float x) { return __builtin_amdgcn_exp2f(x); }
__device__ __forceinline__ float sig_(float x) {
    return __builtin_amdgcn_rcpf(1.0f + exp2_(-1.44269504f * x));
}
__device__ __forceinline__ float tanh_(float x) {
    return 1.0f - 2.0f * __builtin_amdgcn_rcpf(1.0f + exp2_(2.88539008f * x));
}
// precise forms for the fallback path
__device__ __forceinline__ float sigp_(float x) { return 1.0f / (1.0f + __expf(-x)); }
__device__ __forceinline__ float tanhp_(float x) {
    x = fminf(fmaxf(x, -15.0f), 15.0f);
    float e = __expf(-2.0f * x);
    return (1.0f - e) / (1.0f + e);
}

// ==================== weight packing (B-fragment order) ====================
// Wp[l][kk][nt][lane][j] = Wcat_l[kk*32 + 8*(lane>>4) + j][nt*16 + (lane&15)]
// Wcat_l = concat_K(Wx[l] (k<256), Wh[l] (k>=256))  -> [512][1024]
__global__ void pack_weights(const float* __restrict__ Wx, const float* __restrict__ Wh,
                             f16* __restrict__ Wp) {
    int t = blockIdx.x * 256 + threadIdx.x;   // 131072 items
    int lane = t & 63;
    int nt = (t >> 6) & 63;
    int kk = (t >> 12) & 15;
    int l = t >> 16;
    int n = nt * 16 + (lane & 15);
    int kbase = kk * 32 + 8 * (lane >> 4);
    const float* src = (kbase < 256) ? (Wx + (size_t)l * HH * GG + (size_t)kbase * GG + n)
                                     : (Wh + (size_t)l * HH * GG + (size_t)(kbase - 256) * GG + n);
    f16x8 v;
#pragma unroll
    for (int j = 0; j < 8; ++j) v[j] = (f16)src[(size_t)j * GG];
    *(f16x8*)(Wp + (size_t)t * 8) = v;
}

// ==================== embW2 = embed @ Wx0 + b0, CONSUMER-FRAGMENT layout ====================
// embW2[row][cw(8)][arow(16)][ctt'(8)] f16 with ctt' = sub*4 + gate, where
// consumer col = gate*256 + cw*32 + sub*16 + arow. From producer col nt*16+arow
// (nt = gate*16 + cw*2 + sub): cw=(nt>>1)&7, gate=nt>>4, sub=nt&1,
// ctt' = ((nt&1)<<2) | (nt>>4). Each 16-wave-consumer thread reads ONE f16x4
// (its sub's 4 gates) per node row.
__global__ __launch_bounds__(512) void embw_gemm(
    const float* __restrict__ embed, const float* __restrict__ bias,
    const f16* __restrict__ Wp, f16* __restrict__ embW, int vocab)
{
    __shared__ f16 a_lds[32 * HH];   // 16KB, XOR-swizzled rows
    const int tid = threadIdx.x;
    const int lane = tid & 63;
    const int w = tid >> 6;          // 0..7
    const int arow = lane & 15;
    const int g4 = lane >> 4;
    const int r0 = blockIdx.x * 32;

#pragma unroll
    for (int i = 0; i < 4; ++i) {
        int chunk = tid + i * 512;
        int row = chunk >> 6;
        int c4 = chunk & 63;
        int grow = r0 + row; if (grow >= vocab) grow = vocab - 1;
        float4 v = *(const float4*)(embed + (size_t)grow * HH + c4 * 4);
        int idx = row * HH + ((c4 * 4) ^ ((row & 7) << 3));
        *(f16x4*)&a_lds[idx] = (f16x4){(f16)v.x, (f16)v.y, (f16)v.z, (f16)v.w};
    }
    __syncthreads();

    float breg[8];
#pragma unroll
    for (int tt = 0; tt < 8; ++tt) breg[tt] = bias[(w * 8 + tt) * 16 + arow];

    f32x4 acc[2][8];
#pragma unroll
    for (int mt = 0; mt < 2; ++mt)
#pragma unroll
        for (int tt = 0; tt < 8; ++tt)
            acc[mt][tt] = (f32x4){breg[tt], breg[tt], breg[tt], breg[tt]};

    const f16* wl = Wp + (size_t)lane * 8;
#pragma unroll 2
    for (int kk = 0; kk < 8; ++kk) {
        int sw = (kk * 32 + g4 * 8) ^ ((arow & 7) << 3);
        f16x8 a0 = *(const f16x8*)&a_lds[arow * HH + sw];
        f16x8 a1 = *(const f16x8*)&a_lds[(arow + 16) * HH + sw];
        const f16* wkk = wl + (size_t)kk * 64 * 64 * 8;
#pragma unroll
        for (int tt = 0; tt < 8; ++tt) {
            f16x8 b = *(const f16x8*)(wkk + (size_t)(w * 8 + tt) * 64 * 8);
            acc[0][tt] = __builtin_amdgcn_mfma_f32_16x16x32_f16(a0, b, acc[0][tt], 0, 0, 0);
            acc[1][tt] = __builtin_amdgcn_mfma_f32_16x16x32_f16(a1, b, acc[1][tt], 0, 0, 0);
        }
    }

#pragma unroll
    for (int mt = 0; mt < 2; ++mt)
#pragma unroll
        for (int tt = 0; tt < 8; ++tt) {
            int nt = w * 8 + tt;
            int cw = (nt >> 1) & 7;
            int ctt = ((nt & 1) << 2) | (nt >> 4);   // sub*4 + gate
#pragma unroll
            for (int r = 0; r < 4; ++r) {
                int row = r0 + mt * 16 + g4 * 4 + r;
                if (row < vocab)
                    embW[(size_t)row * GG + cw * 128 + arow * 8 + ctt] = (f16)acc[mt][tt][r];
            }
        }
}

// ==================== recurrent kernel ====================
// 128 blocks x 1024 threads (16 waves, 4 waves/SIMD), NB=32. The 16 waves
// PARTITION the B-stream (r14 duplicated it -> 2x bytes -> regression): wave w
// owns col-group wq=w>>1 and gate-half sub=w&1 -> 4 B-frags/kk/wave, 64/kk/CU
// total == r15's bytes, but 2x the waves to saturate the per-CU load pipe
// (r14+r15 evidence: per-CU vector-load BW is the binding resource).
// Full M=32 per wave (acc[2][4]). 1 barrier/step, deferred zx add (f16x4
// compact gathers via ctt' layout). JIT B-loads only (6 spill rounds say so).
#define NB2 32
#define LDH 264    // h row stride (256 + 8 f16 pad)
#define RTH 1024

__global__ __launch_bounds__(RTH, 1) void lstm_rec2(
    const int* __restrict__ data, const float* __restrict__ bias,
    const f16* __restrict__ embW, const f16* __restrict__ Wp,
    float* __restrict__ out)
{
    __shared__ f16 h0s[2][NB2 * LDH];  // 33.8KB double-buffered
    __shared__ f16 h1s[2][NB2 * LDH];  // 33.8KB double-buffered
    __shared__ int toks[NB2 * TT];     // 8KB

    const int tid = threadIdx.x;
    const int lane = tid & 63;
    const int w = tid >> 6;          // 0..15
    const int wq = w >> 1;           // col group 0..7
    const int sub = w & 1;           // gate-half (unit sub-block)
    const int arow = lane & 15;
    const int g4 = lane >> 4;
    const int n0 = blockIdx.x * NB2;

    for (int i = tid; i < NB2 * LDH; i += RTH) {
        h0s[0][i] = (f16)0; h0s[1][i] = (f16)0;
        h1s[0][i] = (f16)0; h1s[1][i] = (f16)0;
    }
    for (int i = tid; i < NB2 * TT; i += RTH) toks[i] = data[n0 * TT + i];

    const int u = wq * 32 + sub * 16 + arow;   // owned hidden unit
    float breg1[4];
#pragma unroll
    for (int g = 0; g < 4; ++g) breg1[g] = bias[GG + g * 256 + u];

    float c0[8], c1[8];
#pragma unroll
    for (int i = 0; i < 8; ++i) { c0[i] = 0.0f; c1[i] = 0.0f; }

    const f16* wl0 = Wp + (size_t)8 * 32768 + (size_t)lane * 8;   // l0 Wh (kk 8..15)
    const f16* wl1 = Wp + (size_t)16 * 32768 + (size_t)lane * 8;  // l1 (kk 0..15)
    const int zoff = wq * 128 + arow * 8 + sub * 4;   // embW2 f16x4 sub-offset

    int cur0 = 0, cur1 = 0;

    __syncthreads();

#pragma unroll 1
    for (int t = 0; t < TT; ++t) {
        // ---- issue zx fragment gathers (f16x4 each; consumed after L0h) ----
        f16x4 zfa0, zfa1, zfa2, zfa3, zfb0, zfb1, zfb2, zfb3;
        {
            int nb = g4 * 4;
            int t0 = toks[(nb + 0) * TT + t];
            int t1 = toks[(nb + 1) * TT + t];
            int t2 = toks[(nb + 2) * TT + t];
            int t3 = toks[(nb + 3) * TT + t];
            zfa0 = *(const f16x4*)(embW + (size_t)t0 * GG + zoff);
            zfa1 = *(const f16x4*)(embW + (size_t)t1 * GG + zoff);
            zfa2 = *(const f16x4*)(embW + (size_t)t2 * GG + zoff);
            zfa3 = *(const f16x4*)(embW + (size_t)t3 * GG + zoff);
        }
        {
            int nb = 16 + g4 * 4;
            int t0 = toks[(nb + 0) * TT + t];
            int t1 = toks[(nb + 1) * TT + t];
            int t2 = toks[(nb + 2) * TT + t];
            int t3 = toks[(nb + 3) * TT + t];
            zfb0 = *(const f16x4*)(embW + (size_t)t0 * GG + zoff);
            zfb1 = *(const f16x4*)(embW + (size_t)t1 * GG + zoff);
            zfb2 = *(const f16x4*)(embW + (size_t)t2 * GG + zoff);
            zfb3 = *(const f16x4*)(embW + (size_t)t3 * GG + zoff);
        }

        // ---- L0 h-part: h0[cur0] @ Wh0 (JIT B-loads), acc starts at ZERO ----
        f32x4 acc[2][4];
#pragma unroll
        for (int mt = 0; mt < 2; ++mt)
#pragma unroll
            for (int g = 0; g < 4; ++g)
                acc[mt][g] = (f32x4){0.0f, 0.0f, 0.0f, 0.0f};

        const f16* h0cur = h0s[cur0];
#pragma unroll
        for (int kk = 0; kk < 8; ++kk) {
            int k0 = kk * 32 + 8 * g4;
            f16x8 a0 = *(const f16x8*)&h0cur[arow * LDH + k0];
            f16x8 a1 = *(const f16x8*)&h0cur[(arow + 16) * LDH + k0];
            const f16* wkk = wl0 + (size_t)kk * 32768;
#pragma unroll
            for (int g = 0; g < 4; ++g) {
                f16x8 b = *(const f16x8*)(wkk + (size_t)(g * 16 + wq * 2 + sub) * 512);
                acc[0][g] = __builtin_amdgcn_mfma_f32_16x16x32_f16(a0, b, acc[0][g], 0, 0, 0);
                acc[1][g] = __builtin_amdgcn_mfma_f32_16x16x32_f16(a1, b, acc[1][g], 0, 0, 0);
            }
        }

        // ---- deferred add: acc += zx (= x@Wx0 + b0); gathers have drained ----
#pragma unroll
        for (int g = 0; g < 4; ++g) {
            acc[0][g][0] += (float)zfa0[g];
            acc[0][g][1] += (float)zfa1[g];
            acc[0][g][2] += (float)zfa2[g];
            acc[0][g][3] += (float)zfa3[g];
            acc[1][g][0] += (float)zfb0[g];
            acc[1][g][1] += (float)zfb1[g];
            acc[1][g][2] += (float)zfb2[g];
            acc[1][g][3] += (float)zfb3[g];
        }

        // ---- L0 gates -> h0[cur0^1] (no barrier: different buffer) ----
        f16* h0new = h0s[cur0 ^ 1];
#pragma unroll
        for (int mt = 0; mt < 2; ++mt)
#pragma unroll
            for (int r = 0; r < 4; ++r) {
                int node = mt * 16 + g4 * 4 + r;
                float i_ = sig_(acc[mt][0][r]);
                float f_ = sig_(acc[mt][1][r]);
                float g_ = tanh_(acc[mt][2][r]);
                float o_ = sig_(acc[mt][3][r]);
                int ci = mt * 4 + r;
                float c = fmaf(f_, c0[ci], i_ * g_);
                c0[ci] = c;
                h0new[node * LDH + u] = (f16)(o_ * tanh_(c));
            }
        __syncthreads();   // THE barrier: h0new visible to all waves for L1

        // ---- L1: [h0_new | h1_prev] @ [Wx1; Wh1] ----
        f32x4 acc1[2][4];
#pragma unroll
        for (int mt = 0; mt < 2; ++mt)
#pragma unroll
            for (int g = 0; g < 4; ++g)
                acc1[mt][g] = (f32x4){breg1[g], breg1[g], breg1[g], breg1[g]};

        const f16* h1cur = h1s[cur1];
#pragma unroll 4
        for (int kk = 0; kk < 16; ++kk) {
            const f16* asrc = (kk < 8) ? (const f16*)h0new : h1cur;
            int k0 = (kk & 7) * 32 + 8 * g4;
            f16x8 a0 = *(const f16x8*)&asrc[arow * LDH + k0];
            f16x8 a1 = *(const f16x8*)&asrc[(arow + 16) * LDH + k0];
            const f16* wkk = wl1 + (size_t)kk * 32768;
#pragma unroll
            for (int g = 0; g < 4; ++g) {
                f16x8 b = *(const f16x8*)(wkk + (size_t)(g * 16 + wq * 2 + sub) * 512);
                acc1[0][g] = __builtin_amdgcn_mfma_f32_16x16x32_f16(a0, b, acc1[0][g], 0, 0, 0);
                acc1[1][g] = __builtin_amdgcn_mfma_f32_16x16x32_f16(a1, b, acc1[1][g], 0, 0, 0);
            }
        }

        // ---- L1 gates -> h1[cur1^1] (no barrier: dbuf) ----
#pragma unroll
        for (int mt = 0; mt < 2; ++mt)
#pragma unroll
            for (int r = 0; r < 4; ++r) {
                int node = mt * 16 + g4 * 4 + r;
                float i_ = sig_(acc1[mt][0][r]);
                float f_ = sig_(acc1[mt][1][r]);
                float g_ = tanh_(acc1[mt][2][r]);
                float o_ = sig_(acc1[mt][3][r]);
                int ci = mt * 4 + r;
                float c = fmaf(f_, c1[ci], i_ * g_);
                c1[ci] = c;
                h1s[cur1 ^ 1][node * LDH + u] = (f16)(o_ * tanh_(c));
            }
        cur0 ^= 1;
        cur1 ^= 1;
    }
    __syncthreads();

    for (int i = tid; i < NB2 * HH; i += RTH) {
        int n = i >> 8, k = i & 255;
        out[(size_t)(n0 + n) * HH + k] = (float)h1s[cur1][n * LDH + k];
    }
}

// ==================== fallback: round-2 MFMA path ====================
__global__ void convert_embed(const float* __restrict__ e, f16* __restrict__ o, int n8) {
    int i = blockIdx.x * 256 + threadIdx.x;
    if (i >= n8) return;
    size_t p = (size_t)i * 8;
    float4 a = *(const float4*)(e + p);
    float4 b = *(const float4*)(e + p + 4);
    f16x8 v = { (f16)a.x, (f16)a.y, (f16)a.z, (f16)a.w,
                (f16)b.x, (f16)b.y, (f16)b.z, (f16)b.w };
    *(f16x8*)(o + p) = v;
}

#define FB 32
#define FTH 512
#define FLD 264
__device__ __forceinline__ void fb_layer_step(
    const f16 (*bx)[FLD], f16 (*bh)[FLD], const f16* __restrict__ wlayer,
    const float* breg_l, float* c_l, int lane, int w)
{
    f32x4 acc[2][8];
#pragma unroll
    for (int mt = 0; mt < 2; ++mt)
#pragma unroll
        for (int tt = 0; tt < 8; ++tt) {
            float b = breg_l[tt];
            acc[mt][tt] = (f32x4){b, b, b, b};
        }
    const int arow = lane & 15;
    const int koff = 8 * (lane >> 4);
    const f16* wl = wlayer + (size_t)lane * 8;
#pragma unroll 2
    for (int kk = 0; kk < 16; ++kk) {
        int k0 = (kk & 7) * 32 + koff;
        const f16(*src)[FLD] = (kk < 8) ? bx : (const f16(*)[FLD])bh;
        f16x8 a0 = *(const f16x8*)&src[arow][k0];
        f16x8 a1 = *(const f16x8*)&src[arow + 16][k0];
        const f16* wkk = wl + (size_t)kk * 64 * 64 * 8;
#pragma unroll
        for (int tt = 0; tt < 8; ++tt) {
            int nt = (tt >> 1) * 16 + w * 2 + (tt & 1);
            f16x8 b = *(const f16x8*)(wkk + (size_t)nt * 64 * 8);
            acc[0][tt] = __builtin_amdgcn_mfma_f32_16x16x32_f16(a0, b, acc[0][tt], 0, 0, 0);
            acc[1][tt] = __builtin_amdgcn_mfma_f32_16x16x32_f16(a1, b, acc[1][tt], 0, 0, 0);
        }
    }
    __syncthreads();
#pragma unroll
    for (int mt = 0; mt < 2; ++mt)
#pragma unroll
        for (int sub = 0; sub < 2; ++sub) {
            f32x4 iv = acc[mt][0 + sub], fv = acc[mt][2 + sub];
            f32x4 gv = acc[mt][4 + sub], ov = acc[mt][6 + sub];
#pragma unroll
            for (int r = 0; r < 4; ++r) {
                float i_ = sigp_(iv[r]), f_ = sigp_(fv[r]), g_ = tanhp_(gv[r]), o_ = sigp_(ov[r]);
                int ci = mt * 8 + sub * 4 + r;
                float c = fmaf(f_, c_l[ci], i_ * g_);
                c_l[ci] = c;
                int node = mt * 16 + (lane >> 4) * 4 + r;
                int unit = w * 32 + sub * 16 + (lane & 15);
                bh[node][unit] = (f16)(o_ * tanhp_(c));
            }
        }
    __syncthreads();
}

__global__ __launch_bounds__(FTH, 2) void lstm_mfma_fb(
    const int* __restrict__ data, const float* __restrict__ bias,
    const f16* __restrict__ emb, const f16* __restrict__ Wp,
    float* __restrict__ out, int vocab)
{
    __shared__ f16 x_lds[FB][FLD];
    __shared__ f16 h0_lds[FB][FLD];
    __shared__ f16 h1_lds[FB][FLD];
    const int tid = threadIdx.x;
    const int lane = tid & 63;
    const int w = tid >> 6;
    const int n0 = blockIdx.x * FB;
    for (int i = tid; i < FB * FLD; i += FTH) {
        (&h0_lds[0][0])[i] = (f16)0.0f; (&h1_lds[0][0])[i] = (f16)0.0f;
    }
    float breg[2][8];
#pragma unroll
    for (int l = 0; l < 2; ++l)
#pragma unroll
        for (int tt = 0; tt < 8; ++tt) {
            int col = (tt >> 1) * 256 + w * 32 + (tt & 1) * 16 + (lane & 15);
            breg[l][tt] = bias[l * GG + col];
        }
    float cst[2][16];
#pragma unroll
    for (int i = 0; i < 32; ++i) (&cst[0][0])[i] = 0.0f;
    __syncthreads();
    const f16* Wp0 = Wp;
    const f16* Wp1 = Wp + (size_t)16 * 64 * 64 * 8;
    for (int t = 0; t < TT; ++t) {
        {
            int n = tid >> 4;
            int cg = (tid & 15) * 16;
            int row = data[(n0 + n) * TT + t];
            row = min(max(row, 0), vocab - 1);
            const f16* src = emb + (size_t)row * HH + cg;
            *(f16x8*)&x_lds[n][cg] = *(const f16x8*)src;
            *(f16x8*)&x_lds[n][cg + 8] = *(const f16x8*)(src + 8);
        }
        __syncthreads();
        fb_layer_step(x_lds, h0_lds, Wp0, breg[0], cst[0], lane, w);
        fb_layer_step((const f16(*)[FLD])h0_lds, h1_lds, Wp1, breg[1], cst[1], lane, w);
    }
    for (int i = tid; i < FB * HH; i += FTH) {
        int n = i >> 8, k = i & 255;
        out[(size_t)(n0 + n) * HH + k] = (float)h1_lds[n][k];
    }
}

// ==================== launcher ====================
extern "C" void kernel_launch(void* const* d_in, const int* in_sizes, int n_in,
                              void* d_out, int out_size, void* d_ws, size_t ws_size,
                              hipStream_t stream) {
    const int* data = (const int*)d_in[0];
    const float* embed = (const float*)d_in[1];
    const float* Wx = (const float*)d_in[2];
    const float* Wh = (const float*)d_in[3];
    const float* bias = (const float*)d_in[4];
    float* out = (float*)d_out;
    const int vocab = in_sizes[1] / HH;       // 30000
    const int nNodes = in_sizes[0] / TT;      // 4096

    const size_t wp_bytes = (size_t)2 * 16 * 64 * 64 * 8 * 2;   // 2 MB
    const size_t embw_bytes = (size_t)vocab * GG * 2;           // 61.4 MB
    const size_t emb16_bytes = (size_t)vocab * HH * 2;          // 15.4 MB

    if (ws_size >= embw_bytes + wp_bytes) {
        f16* embW = (f16*)d_ws;
        f16* Wp = (f16*)((char*)d_ws + embw_bytes);
        pack_weights<<<dim3(512), dim3(256), 0, stream>>>(Wx, Wh, Wp);
        embw_gemm<<<dim3((vocab + 31) / 32), dim3(512), 0, stream>>>(embed, bias, Wp, embW, vocab);
        lstm_rec2<<<dim3(nNodes / NB2), dim3(RTH), 0, stream>>>(data, bias, embW, Wp, out);
        return;
    }
    // fallback: fp16 embed table + packed weights (r2 path)
    f16* emb_h = (f16*)d_ws;
    f16* Wp = (f16*)((char*)d_ws + emb16_bytes);
    int n8 = in_sizes[1] / 8;
    convert_embed<<<dim3((n8 + 255) / 256), dim3(256), 0, stream>>>(embed, emb_h, n8);
    pack_weights<<<dim3(512), dim3(256), 0, stream>>>(Wx, Wh, Wp);
    lstm_mfma_fb<<<dim3(nNodes / FB), dim3(FTH), 0, stream>>>(data, bias, emb_h, Wp, out, vocab);
}

// Round 18
// 1114.140 us; speedup vs baseline: 2.6021x; 1.9901x over previous
//
#include <hip/hip_runtime.h>
#include <hip/hip_bf16.h>

// Problem: N=4096 nodes, T=64, V=30000, H=256, L=2 layers, gates=4H=1024
#define TT 64
#define HH 256
#define GG 1024

typedef _Float16 f16;
typedef __attribute__((ext_vector_type(8))) _Float16 f16x8;
typedef __attribute__((ext_vector_type(4))) _Float16 f16x4;
typedef __attribute__((ext_vector_type(4))) float f32x4;

// fast activations via v_exp_f32 (2^x) + v_rcp_f32 (validated r5-r17: absmax 1.22e-4).
__device__ __forceinline__ float exp2_(float x) { return __builtin_amdgcn_exp2f(x); }
__device__ __forceinline__ float sig_(float x) {
    return __builtin_amdgcn_rcpf(1.0f + exp2_(-1.44269504f * x));
}
__device__ __forceinline__ float tanh_(float x) {
    return 1.0f - 2.0f * __builtin_amdgcn_rcpf(1.0f + exp2_(2.88539008f * x));
}
// precise forms for the fallback path
__device__ __forceinline__ float sigp_(float x) { return 1.0f / (1.0f + __expf(-x)); }
__device__ __forceinline__ float tanhp_(float x) {
    x = fminf(fmaxf(x, -15.0f), 15.0f);
    float e = __expf(-2.0f * x);
    return (1.0f - e) / (1.0f + e);
}

// ==================== weight packing (B-fragment order) ====================
// Wp[l][kk][nt][lane][j] = Wcat_l[kk*32 + 8*(lane>>4) + j][nt*16 + (lane&15)]
// Wcat_l = concat_K(Wx[l] (k<256), Wh[l] (k>=256))  -> [512][1024]
__global__ void pack_weights(const float* __restrict__ Wx, const float* __restrict__ Wh,
                             f16* __restrict__ Wp) {
    int t = blockIdx.x * 256 + threadIdx.x;   // 131072 items
    int lane = t & 63;
    int nt = (t >> 6) & 63;
    int kk = (t >> 12) & 15;
    int l = t >> 16;
    int n = nt * 16 + (lane & 15);
    int kbase = kk * 32 + 8 * (lane >> 4);
    const float* src = (kbase < 256) ? (Wx + (size_t)l * HH * GG + (size_t)kbase * GG + n)
                                     : (Wh + (size_t)l * HH * GG + (size_t)(kbase - 256) * GG + n);
    f16x8 v;
#pragma unroll
    for (int j = 0; j < 8; ++j) v[j] = (f16)src[(size_t)j * GG];
    *(f16x8*)(Wp + (size_t)t * 8) = v;
}

// ==================== embW2 = embed @ Wx0 + b0, CONSUMER-FRAGMENT layout ====================
// embW2[row][cw(8)][arow(16)][ctt(8)] f16; consumer col = (ctt>>1)*256 + cw*32 +
// (ctt&1)*16 + arow. Bijection from producer col nt*16+arow: cw=(nt>>1)&7,
// ctt=((nt>>4)<<1)|(nt&1).
__global__ __launch_bounds__(512) void embw_gemm(
    const float* __restrict__ embed, const float* __restrict__ bias,
    const f16* __restrict__ Wp, f16* __restrict__ embW, int vocab)
{
    __shared__ f16 a_lds[32 * HH];   // 16KB, XOR-swizzled rows
    const int tid = threadIdx.x;
    const int lane = tid & 63;
    const int w = tid >> 6;          // 0..7
    const int arow = lane & 15;
    const int g4 = lane >> 4;
    const int r0 = blockIdx.x * 32;

#pragma unroll
    for (int i = 0; i < 4; ++i) {
        int chunk = tid + i * 512;
        int row = chunk >> 6;
        int c4 = chunk & 63;
        int grow = r0 + row; if (grow >= vocab) grow = vocab - 1;
        float4 v = *(const float4*)(embed + (size_t)grow * HH + c4 * 4);
        int idx = row * HH + ((c4 * 4) ^ ((row & 7) << 3));
        *(f16x4*)&a_lds[idx] = (f16x4){(f16)v.x, (f16)v.y, (f16)v.z, (f16)v.w};
    }
    __syncthreads();

    float breg[8];
#pragma unroll
    for (int tt = 0; tt < 8; ++tt) breg[tt] = bias[(w * 8 + tt) * 16 + arow];

    f32x4 acc[2][8];
#pragma unroll
    for (int mt = 0; mt < 2; ++mt)
#pragma unroll
        for (int tt = 0; tt < 8; ++tt)
            acc[mt][tt] = (f32x4){breg[tt], breg[tt], breg[tt], breg[tt]};

    const f16* wl = Wp + (size_t)lane * 8;
#pragma unroll 2
    for (int kk = 0; kk < 8; ++kk) {
        int sw = (kk * 32 + g4 * 8) ^ ((arow & 7) << 3);
        f16x8 a0 = *(const f16x8*)&a_lds[arow * HH + sw];
        f16x8 a1 = *(const f16x8*)&a_lds[(arow + 16) * HH + sw];
        const f16* wkk = wl + (size_t)kk * 64 * 64 * 8;
#pragma unroll
        for (int tt = 0; tt < 8; ++tt) {
            f16x8 b = *(const f16x8*)(wkk + (size_t)(w * 8 + tt) * 64 * 8);
            acc[0][tt] = __builtin_amdgcn_mfma_f32_16x16x32_f16(a0, b, acc[0][tt], 0, 0, 0);
            acc[1][tt] = __builtin_amdgcn_mfma_f32_16x16x32_f16(a1, b, acc[1][tt], 0, 0, 0);
        }
    }

#pragma unroll
    for (int mt = 0; mt < 2; ++mt)
#pragma unroll
        for (int tt = 0; tt < 8; ++tt) {
            int nt = w * 8 + tt;
            int cw = (nt >> 1) & 7;
            int ctt = ((nt >> 4) << 1) | (nt & 1);
#pragma unroll
            for (int r = 0; r < 4; ++r) {
                int row = r0 + mt * 16 + g4 * 4 + r;
                if (row < vocab)
                    embW[(size_t)row * GG + cw * 128 + arow * 8 + ctt] = (f16)acc[mt][tt][r];
            }
        }
}

// ==================== recurrent kernel (r15 = best known: 1113us) ====================
// 128 blocks x 512 threads, NB=32. 1 barrier/step, deferred zx add (T14),
// h0+h1 double-buffered, JIT B-loads, L1 kk unroll 4.
// DO NOT add register multibuffering (spills at the 128-VGPR wall: r5/6/7/9/12/16)
// nor LDS weight staging (barrier-bound: r12) nor wave splits (r14/r17).
#define NB2 32
#define LDH 264    // h row stride (256 + 8 f16 pad)

__global__ __launch_bounds__(512, 1) void lstm_rec2(
    const int* __restrict__ data, const float* __restrict__ bias,
    const f16* __restrict__ embW, const f16* __restrict__ Wp,
    float* __restrict__ out)
{
    __shared__ f16 h0s[2][NB2 * LDH];  // 33.8KB double-buffered
    __shared__ f16 h1s[2][NB2 * LDH];  // 33.8KB double-buffered
    __shared__ int toks[NB2 * TT];     // 8KB

    const int tid = threadIdx.x;
    const int lane = tid & 63;
    const int w = tid >> 6;          // 0..7
    const int arow = lane & 15;
    const int g4 = lane >> 4;
    const int n0 = blockIdx.x * NB2;

    for (int i = tid; i < NB2 * LDH; i += 512) {
        h0s[0][i] = (f16)0; h0s[1][i] = (f16)0;
        h1s[0][i] = (f16)0; h1s[1][i] = (f16)0;
    }
    for (int i = tid; i < NB2 * TT; i += 512) toks[i] = data[n0 * TT + i];

    float breg1[8];
#pragma unroll
    for (int tt = 0; tt < 8; ++tt) {
        int col = (tt >> 1) * 256 + w * 32 + (tt & 1) * 16 + arow;
        breg1[tt] = bias[GG + col];
    }

    float c0[16], c1[16];
#pragma unroll
    for (int i = 0; i < 16; ++i) { c0[i] = 0.0f; c1[i] = 0.0f; }

    const f16* wl0 = Wp + (size_t)8 * 64 * 64 * 8 + (size_t)lane * 8;   // l0 Wh (kk 8..15)
    const f16* wl1 = Wp + (size_t)16 * 64 * 64 * 8 + (size_t)lane * 8;  // l1 (kk 0..15)
    const int zoff = w * 128 + arow * 8;   // embW2 fragment sub-offset

    int cur0 = 0, cur1 = 0;

    __syncthreads();

#pragma unroll 1
    for (int t = 0; t < TT; ++t) {
        // ---- issue zx fragment gathers (NOT consumed until after L0h) ----
        f16x8 zfa0, zfa1, zfa2, zfa3, zfb0, zfb1, zfb2, zfb3;
        {
            int nb = g4 * 4;
            int t0 = toks[(nb + 0) * TT + t];
            int t1 = toks[(nb + 1) * TT + t];
            int t2 = toks[(nb + 2) * TT + t];
            int t3 = toks[(nb + 3) * TT + t];
            zfa0 = *(const f16x8*)(embW + (size_t)t0 * GG + zoff);
            zfa1 = *(const f16x8*)(embW + (size_t)t1 * GG + zoff);
            zfa2 = *(const f16x8*)(embW + (size_t)t2 * GG + zoff);
            zfa3 = *(const f16x8*)(embW + (size_t)t3 * GG + zoff);
        }
        {
            int nb = 16 + g4 * 4;
            int t0 = toks[(nb + 0) * TT + t];
            int t1 = toks[(nb + 1) * TT + t];
            int t2 = toks[(nb + 2) * TT + t];
            int t3 = toks[(nb + 3) * TT + t];
            zfb0 = *(const f16x8*)(embW + (size_t)t0 * GG + zoff);
            zfb1 = *(const f16x8*)(embW + (size_t)t1 * GG + zoff);
            zfb2 = *(const f16x8*)(embW + (size_t)t2 * GG + zoff);
            zfb3 = *(const f16x8*)(embW + (size_t)t3 * GG + zoff);
        }

        // ---- L0 h-part: h0[cur0] @ Wh0 (JIT B-loads), acc starts at ZERO ----
        f32x4 acc[2][8];
#pragma unroll
        for (int mt = 0; mt < 2; ++mt)
#pragma unroll
            for (int tt = 0; tt < 8; ++tt)
                acc[mt][tt] = (f32x4){0.0f, 0.0f, 0.0f, 0.0f};

        const f16* h0cur = h0s[cur0];
#pragma unroll 2
        for (int kk = 0; kk < 8; ++kk) {
            int k0 = kk * 32 + 8 * g4;
            f16x8 a0 = *(const f16x8*)&h0cur[arow * LDH + k0];
            f16x8 a1 = *(const f16x8*)&h0cur[(arow + 16) * LDH + k0];
            const f16* wkk = wl0 + (size_t)kk * 64 * 64 * 8;
#pragma unroll
            for (int tt = 0; tt < 8; ++tt) {
                int nt = (tt >> 1) * 16 + w * 2 + (tt & 1);
                f16x8 b = *(const f16x8*)(wkk + (size_t)nt * 64 * 8);
                acc[0][tt] = __builtin_amdgcn_mfma_f32_16x16x32_f16(a0, b, acc[0][tt], 0, 0, 0);
                acc[1][tt] = __builtin_amdgcn_mfma_f32_16x16x32_f16(a1, b, acc[1][tt], 0, 0, 0);
            }
        }

        // ---- deferred add: acc += zx (= x@Wx0 + b0); gathers have drained ----
#pragma unroll
        for (int tt = 0; tt < 8; ++tt) {
            acc[0][tt][0] += (float)zfa0[tt];
            acc[0][tt][1] += (float)zfa1[tt];
            acc[0][tt][2] += (float)zfa2[tt];
            acc[0][tt][3] += (float)zfa3[tt];
            acc[1][tt][0] += (float)zfb0[tt];
            acc[1][tt][1] += (float)zfb1[tt];
            acc[1][tt][2] += (float)zfb2[tt];
            acc[1][tt][3] += (float)zfb3[tt];
        }

        // ---- L0 gates -> h0[cur0^1] (no barrier: different buffer) ----
        f16* h0new = h0s[cur0 ^ 1];
#pragma unroll
        for (int mt = 0; mt < 2; ++mt)
#pragma unroll
            for (int sub = 0; sub < 2; ++sub)
#pragma unroll
                for (int r = 0; r < 4; ++r) {
                    int node = mt * 16 + g4 * 4 + r;
                    float i_ = sig_(acc[mt][0 + sub][r]);
                    float f_ = sig_(acc[mt][2 + sub][r]);
                    float g_ = tanh_(acc[mt][4 + sub][r]);
                    float o_ = sig_(acc[mt][6 + sub][r]);
                    int ci = mt * 8 + sub * 4 + r;
                    float c = fmaf(f_, c0[ci], i_ * g_);
                    c0[ci] = c;
                    int u = w * 32 + sub * 16 + arow;
                    h0new[node * LDH + u] = (f16)(o_ * tanh_(c));
                }
        __syncthreads();   // THE barrier: h0new visible to all waves for L1

        // ---- L1: [h0_new | h1_prev] @ [Wx1; Wh1] ----
        f32x4 acc1[2][8];
#pragma unroll
        for (int mt = 0; mt < 2; ++mt)
#pragma unroll
            for (int tt = 0; tt < 8; ++tt)
                acc1[mt][tt] = (f32x4){breg1[tt], breg1[tt], breg1[tt], breg1[tt]};

        const f16* h1cur = h1s[cur1];
#pragma unroll 4
        for (int kk = 0; kk < 16; ++kk) {
            const f16* asrc = (kk < 8) ? (const f16*)h0new : h1cur;
            int k0 = (kk & 7) * 32 + 8 * g4;
            f16x8 a0 = *(const f16x8*)&asrc[arow * LDH + k0];
            f16x8 a1 = *(const f16x8*)&asrc[(arow + 16) * LDH + k0];
            const f16* wkk = wl1 + (size_t)kk * 64 * 64 * 8;
#pragma unroll
            for (int tt = 0; tt < 8; ++tt) {
                int nt = (tt >> 1) * 16 + w * 2 + (tt & 1);
                f16x8 b = *(const f16x8*)(wkk + (size_t)nt * 64 * 8);
                acc1[0][tt] = __builtin_amdgcn_mfma_f32_16x16x32_f16(a0, b, acc1[0][tt], 0, 0, 0);
                acc1[1][tt] = __builtin_amdgcn_mfma_f32_16x16x32_f16(a1, b, acc1[1][tt], 0, 0, 0);
            }
        }

        // ---- L1 gates -> h1[cur1^1] (no barrier: dbuf) ----
#pragma unroll
        for (int mt = 0; mt < 2; ++mt)
#pragma unroll
            for (int sub = 0; sub < 2; ++sub)
#pragma unroll
                for (int r = 0; r < 4; ++r) {
                    int node = mt * 16 + g4 * 4 + r;
                    float i_ = sig_(acc1[mt][0 + sub][r]);
                    float f_ = sig_(acc1[mt][2 + sub][r]);
                    float g_ = tanh_(acc1[mt][4 + sub][r]);
                    float o_ = sig_(acc1[mt][6 + sub][r]);
                    int ci = mt * 8 + sub * 4 + r;
                    float c = fmaf(f_, c1[ci], i_ * g_);
                    c1[ci] = c;
                    int u = w * 32 + sub * 16 + arow;
                    h1s[cur1 ^ 1][node * LDH + u] = (f16)(o_ * tanh_(c));
                }
        cur0 ^= 1;
        cur1 ^= 1;
    }
    __syncthreads();

    for (int i = tid; i < NB2 * HH; i += 512) {
        int n = i >> 8, k = i & 255;
        out[(size_t)(n0 + n) * HH + k] = (float)h1s[cur1][n * LDH + k];
    }
}

// ==================== fallback: round-2 MFMA path ====================
__global__ void convert_embed(const float* __restrict__ e, f16* __restrict__ o, int n8) {
    int i = blockIdx.x * 256 + threadIdx.x;
    if (i >= n8) return;
    size_t p = (size_t)i * 8;
    float4 a = *(const float4*)(e + p);
    float4 b = *(const float4*)(e + p + 4);
    f16x8 v = { (f16)a.x, (f16)a.y, (f16)a.z, (f16)a.w,
                (f16)b.x, (f16)b.y, (f16)b.z, (f16)b.w };
    *(f16x8*)(o + p) = v;
}

#define FB 32
#define FTH 512
#define FLD 264
__device__ __forceinline__ void fb_layer_step(
    const f16 (*bx)[FLD], f16 (*bh)[FLD], const f16* __restrict__ wlayer,
    const float* breg_l, float* c_l, int lane, int w)
{
    f32x4 acc[2][8];
#pragma unroll
    for (int mt = 0; mt < 2; ++mt)
#pragma unroll
        for (int tt = 0; tt < 8; ++tt) {
            float b = breg_l[tt];
            acc[mt][tt] = (f32x4){b, b, b, b};
        }
    const int arow = lane & 15;
    const int koff = 8 * (lane >> 4);
    const f16* wl = wlayer + (size_t)lane * 8;
#pragma unroll 2
    for (int kk = 0; kk < 16; ++kk) {
        int k0 = (kk & 7) * 32 + koff;
        const f16(*src)[FLD] = (kk < 8) ? bx : (const f16(*)[FLD])bh;
        f16x8 a0 = *(const f16x8*)&src[arow][k0];
        f16x8 a1 = *(const f16x8*)&src[arow + 16][k0];
        const f16* wkk = wl + (size_t)kk * 64 * 64 * 8;
#pragma unroll
        for (int tt = 0; tt < 8; ++tt) {
            int nt = (tt >> 1) * 16 + w * 2 + (tt & 1);
            f16x8 b = *(const f16x8*)(wkk + (size_t)nt * 64 * 8);
            acc[0][tt] = __builtin_amdgcn_mfma_f32_16x16x32_f16(a0, b, acc[0][tt], 0, 0, 0);
            acc[1][tt] = __builtin_amdgcn_mfma_f32_16x16x32_f16(a1, b, acc[1][tt], 0, 0, 0);
        }
    }
    __syncthreads();
#pragma unroll
    for (int mt = 0; mt < 2; ++mt)
#pragma unroll
        for (int sub = 0; sub < 2; ++sub) {
            f32x4 iv = acc[mt][0 + sub], fv = acc[mt][2 + sub];
            f32x4 gv = acc[mt][4 + sub], ov = acc[mt][6 + sub];
#pragma unroll
            for (int r = 0; r < 4; ++r) {
                float i_ = sigp_(iv[r]), f_ = sigp_(fv[r]), g_ = tanhp_(gv[r]), o_ = sigp_(ov[r]);
                int ci = mt * 8 + sub * 4 + r;
                float c = fmaf(f_, c_l[ci], i_ * g_);
                c_l[ci] = c;
                int node = mt * 16 + (lane >> 4) * 4 + r;
                int unit = w * 32 + sub * 16 + (lane & 15);
                bh[node][unit] = (f16)(o_ * tanhp_(c));
            }
        }
    __syncthreads();
}

__global__ __launch_bounds__(FTH, 2) void lstm_mfma_fb(
    const int* __restrict__ data, const float* __restrict__ bias,
    const f16* __restrict__ emb, const f16* __restrict__ Wp,
    float* __restrict__ out, int vocab)
{
    __shared__ f16 x_lds[FB][FLD];
    __shared__ f16 h0_lds[FB][FLD];
    __shared__ f16 h1_lds[FB][FLD];
    const int tid = threadIdx.x;
    const int lane = tid & 63;
    const int w = tid >> 6;
    const int n0 = blockIdx.x * FB;
    for (int i = tid; i < FB * FLD; i += FTH) {
        (&h0_lds[0][0])[i] = (f16)0.0f; (&h1_lds[0][0])[i] = (f16)0.0f;
    }
    float breg[2][8];
#pragma unroll
    for (int l = 0; l < 2; ++l)
#pragma unroll
        for (int tt = 0; tt < 8; ++tt) {
            int col = (tt >> 1) * 256 + w * 32 + (tt & 1) * 16 + (lane & 15);
            breg[l][tt] = bias[l * GG + col];
        }
    float cst[2][16];
#pragma unroll
    for (int i = 0; i < 32; ++i) (&cst[0][0])[i] = 0.0f;
    __syncthreads();
    const f16* Wp0 = Wp;
    const f16* Wp1 = Wp + (size_t)16 * 64 * 64 * 8;
    for (int t = 0; t < TT; ++t) {
        {
            int n = tid >> 4;
            int cg = (tid & 15) * 16;
            int row = data[(n0 + n) * TT + t];
            row = min(max(row, 0), vocab - 1);
            const f16* src = emb + (size_t)row * HH + cg;
            *(f16x8*)&x_lds[n][cg] = *(const f16x8*)src;
            *(f16x8*)&x_lds[n][cg + 8] = *(const f16x8*)(src + 8);
        }
        __syncthreads();
        fb_layer_step(x_lds, h0_lds, Wp0, breg[0], cst[0], lane, w);
        fb_layer_step((const f16(*)[FLD])h0_lds, h1_lds, Wp1, breg[1], cst[1], lane, w);
    }
    for (int i = tid; i < FB * HH; i += FTH) {
        int n = i >> 8, k = i & 255;
        out[(size_t)(n0 + n) * HH + k] = (float)h1_lds[n][k];
    }
}

// ==================== launcher ====================
extern "C" void kernel_launch(void* const* d_in, const int* in_sizes, int n_in,
                              void* d_out, int out_size, void* d_ws, size_t ws_size,
                              hipStream_t stream) {
    const int* data = (const int*)d_in[0];
    const float* embed = (const float*)d_in[1];
    const float* Wx = (const float*)d_in[2];
    const float* Wh = (const float*)d_in[3];
    const float* bias = (const float*)d_in[4];
    float* out = (float*)d_out;
    const int vocab = in_sizes[1] / HH;       // 30000
    const int nNodes = in_sizes[0] / TT;      // 4096

    const size_t wp_bytes = (size_t)2 * 16 * 64 * 64 * 8 * 2;   // 2 MB
    const size_t embw_bytes = (size_t)vocab * GG * 2;           // 61.4 MB
    const size_t emb16_bytes = (size_t)vocab * HH * 2;          // 15.4 MB

    if (ws_size >= embw_bytes + wp_bytes) {
        f16* embW = (f16*)d_ws;
        f16* Wp = (f16*)((char*)d_ws + embw_bytes);
        pack_weights<<<dim3(512), dim3(256), 0, stream>>>(Wx, Wh, Wp);
        embw_gemm<<<dim3((vocab + 31) / 32), dim3(512), 0, stream>>>(embed, bias, Wp, embW, vocab);
        lstm_rec2<<<dim3(nNodes / NB2), dim3(512), 0, stream>>>(data, bias, embW, Wp, out);
        return;
    }
    // fallback: fp16 embed table + packed weights (r2 path)
    f16* emb_h = (f16*)d_ws;
    f16* Wp = (f16*)((char*)d_ws + emb16_bytes);
    int n8 = in_sizes[1] / 8;
    convert_embed<<<dim3((n8 + 255) / 256), dim3(256), 0, stream>>>(embed, emb_h, n8);
    pack_weights<<<dim3(512), dim3(256), 0, stream>>>(Wx, Wh, Wp);
    lstm_mfma_fb<<<dim3(nNodes / FB), dim3(FTH), 0, stream>>>(data, bias, emb_h, Wp, out, vocab);
}

// Round 19
// 1108.578 us; speedup vs baseline: 2.6152x; 1.0050x over previous
//
#include <hip/hip_runtime.h>
#include <hip/hip_bf16.h>

// Problem: N=4096 nodes, T=64, V=30000, H=256, L=2 layers, gates=4H=1024
#define TT 64
#define HH 256
#define GG 1024

typedef _Float16 f16;
typedef __attribute__((ext_vector_type(8))) _Float16 f16x8;
typedef __attribute__((ext_vector_type(4))) _Float16 f16x4;
typedef __attribute__((ext_vector_type(4))) float f32x4;

// fast activations via v_exp_f32 (2^x) + v_rcp_f32 (validated r5-r18: absmax 1.22e-4).
__device__ __forceinline__ float exp2_(float x) { return __builtin_amdgcn_exp2f(x); }
__device__ __forceinline__ float sig_(float x) {
    return __builtin_amdgcn_rcpf(1.0f + exp2_(-1.44269504f * x));
}
__device__ __forceinline__ float tanh_(float x) {
    return 1.0f - 2.0f * __builtin_amdgcn_rcpf(1.0f + exp2_(2.88539008f * x));
}
// precise forms for the fallback path
__device__ __forceinline__ float sigp_(float x) { return 1.0f / (1.0f + __expf(-x)); }
__device__ __forceinline__ float tanhp_(float x) {
    x = fminf(fmaxf(x, -15.0f), 15.0f);
    float e = __expf(-2.0f * x);
    return (1.0f - e) / (1.0f + e);
}

// ==================== weight packing (B-fragment order) ====================
// Wp[l][kk][nt][lane][j] = Wcat_l[kk*32 + 8*(lane>>4) + j][nt*16 + (lane&15)]
// Wcat_l = concat_K(Wx[l] (k<256), Wh[l] (k>=256))  -> [512][1024]
__global__ void pack_weights(const float* __restrict__ Wx, const float* __restrict__ Wh,
                             f16* __restrict__ Wp) {
    int t = blockIdx.x * 256 + threadIdx.x;   // 131072 items
    int lane = t & 63;
    int nt = (t >> 6) & 63;
    int kk = (t >> 12) & 15;
    int l = t >> 16;
    int n = nt * 16 + (lane & 15);
    int kbase = kk * 32 + 8 * (lane >> 4);
    const float* src = (kbase < 256) ? (Wx + (size_t)l * HH * GG + (size_t)kbase * GG + n)
                                     : (Wh + (size_t)l * HH * GG + (size_t)(kbase - 256) * GG + n);
    f16x8 v;
#pragma unroll
    for (int j = 0; j < 8; ++j) v[j] = (f16)src[(size_t)j * GG];
    *(f16x8*)(Wp + (size_t)t * 8) = v;
}

// ==================== embW2 = embed @ Wx0 + b0, CONSUMER-FRAGMENT layout ====================
// embW2[row][cw(8)][arow(16)][ctt(8)] f16; consumer col = (ctt>>1)*256 + cw*32 +
// (ctt&1)*16 + arow. Bijection from producer col nt*16+arow: cw=(nt>>1)&7,
// ctt=((nt>>4)<<1)|(nt&1).
__global__ __launch_bounds__(512) void embw_gemm(
    const float* __restrict__ embed, const float* __restrict__ bias,
    const f16* __restrict__ Wp, f16* __restrict__ embW, int vocab)
{
    __shared__ f16 a_lds[32 * HH];   // 16KB, XOR-swizzled rows
    const int tid = threadIdx.x;
    const int lane = tid & 63;
    const int w = tid >> 6;          // 0..7
    const int arow = lane & 15;
    const int g4 = lane >> 4;
    const int r0 = blockIdx.x * 32;

#pragma unroll
    for (int i = 0; i < 4; ++i) {
        int chunk = tid + i * 512;
        int row = chunk >> 6;
        int c4 = chunk & 63;
        int grow = r0 + row; if (grow >= vocab) grow = vocab - 1;
        float4 v = *(const float4*)(embed + (size_t)grow * HH + c4 * 4);
        int idx = row * HH + ((c4 * 4) ^ ((row & 7) << 3));
        *(f16x4*)&a_lds[idx] = (f16x4){(f16)v.x, (f16)v.y, (f16)v.z, (f16)v.w};
    }
    __syncthreads();

    float breg[8];
#pragma unroll
    for (int tt = 0; tt < 8; ++tt) breg[tt] = bias[(w * 8 + tt) * 16 + arow];

    f32x4 acc[2][8];
#pragma unroll
    for (int mt = 0; mt < 2; ++mt)
#pragma unroll
        for (int tt = 0; tt < 8; ++tt)
            acc[mt][tt] = (f32x4){breg[tt], breg[tt], breg[tt], breg[tt]};

    const f16* wl = Wp + (size_t)lane * 8;
#pragma unroll 2
    for (int kk = 0; kk < 8; ++kk) {
        int sw = (kk * 32 + g4 * 8) ^ ((arow & 7) << 3);
        f16x8 a0 = *(const f16x8*)&a_lds[arow * HH + sw];
        f16x8 a1 = *(const f16x8*)&a_lds[(arow + 16) * HH + sw];
        const f16* wkk = wl + (size_t)kk * 64 * 64 * 8;
#pragma unroll
        for (int tt = 0; tt < 8; ++tt) {
            f16x8 b = *(const f16x8*)(wkk + (size_t)(w * 8 + tt) * 64 * 8);
            acc[0][tt] = __builtin_amdgcn_mfma_f32_16x16x32_f16(a0, b, acc[0][tt], 0, 0, 0);
            acc[1][tt] = __builtin_amdgcn_mfma_f32_16x16x32_f16(a1, b, acc[1][tt], 0, 0, 0);
        }
    }

#pragma unroll
    for (int mt = 0; mt < 2; ++mt)
#pragma unroll
        for (int tt = 0; tt < 8; ++tt) {
            int nt = w * 8 + tt;
            int cw = (nt >> 1) & 7;
            int ctt = ((nt >> 4) << 1) | (nt & 1);
#pragma unroll
            for (int r = 0; r < 4; ++r) {
                int row = r0 + mt * 16 + g4 * 4 + r;
                if (row < vocab)
                    embW[(size_t)row * GG + cw * 128 + arow * 8 + ctt] = (f16)acc[mt][tt][r];
            }
        }
}

// ==================== recurrent kernel (r15 base + T5 s_setprio around MFMA) ====================
// 128 blocks x 512 threads, NB=32. 1 barrier/step, deferred zx add (T14),
// h0+h1 double-buffered, JIT B-loads, L1 kk unroll 4.
// T5: waves drift freely across the 24-kk inter-barrier stretch -> role
// diversity exists -> setprio(1) lets MFMA-dense waves preempt load-issuing
// ones (attn analog +4-7%, m191). Single-variable change vs r15/r18.
// DO NOT add register multibuffering (spills at the 128-VGPR wall: r5/6/7/9/12/16)
// nor LDS weight staging (barrier-bound: r12) nor wave splits (r14/r17).
#define NB2 32
#define LDH 264    // h row stride (256 + 8 f16 pad)

__global__ __launch_bounds__(512, 1) void lstm_rec2(
    const int* __restrict__ data, const float* __restrict__ bias,
    const f16* __restrict__ embW, const f16* __restrict__ Wp,
    float* __restrict__ out)
{
    __shared__ f16 h0s[2][NB2 * LDH];  // 33.8KB double-buffered
    __shared__ f16 h1s[2][NB2 * LDH];  // 33.8KB double-buffered
    __shared__ int toks[NB2 * TT];     // 8KB

    const int tid = threadIdx.x;
    const int lane = tid & 63;
    const int w = tid >> 6;          // 0..7
    const int arow = lane & 15;
    const int g4 = lane >> 4;
    const int n0 = blockIdx.x * NB2;

    for (int i = tid; i < NB2 * LDH; i += 512) {
        h0s[0][i] = (f16)0; h0s[1][i] = (f16)0;
        h1s[0][i] = (f16)0; h1s[1][i] = (f16)0;
    }
    for (int i = tid; i < NB2 * TT; i += 512) toks[i] = data[n0 * TT + i];

    float breg1[8];
#pragma unroll
    for (int tt = 0; tt < 8; ++tt) {
        int col = (tt >> 1) * 256 + w * 32 + (tt & 1) * 16 + arow;
        breg1[tt] = bias[GG + col];
    }

    float c0[16], c1[16];
#pragma unroll
    for (int i = 0; i < 16; ++i) { c0[i] = 0.0f; c1[i] = 0.0f; }

    const f16* wl0 = Wp + (size_t)8 * 64 * 64 * 8 + (size_t)lane * 8;   // l0 Wh (kk 8..15)
    const f16* wl1 = Wp + (size_t)16 * 64 * 64 * 8 + (size_t)lane * 8;  // l1 (kk 0..15)
    const int zoff = w * 128 + arow * 8;   // embW2 fragment sub-offset

    int cur0 = 0, cur1 = 0;

    __syncthreads();

#pragma unroll 1
    for (int t = 0; t < TT; ++t) {
        // ---- issue zx fragment gathers (NOT consumed until after L0h) ----
        f16x8 zfa0, zfa1, zfa2, zfa3, zfb0, zfb1, zfb2, zfb3;
        {
            int nb = g4 * 4;
            int t0 = toks[(nb + 0) * TT + t];
            int t1 = toks[(nb + 1) * TT + t];
            int t2 = toks[(nb + 2) * TT + t];
            int t3 = toks[(nb + 3) * TT + t];
            zfa0 = *(const f16x8*)(embW + (size_t)t0 * GG + zoff);
            zfa1 = *(const f16x8*)(embW + (size_t)t1 * GG + zoff);
            zfa2 = *(const f16x8*)(embW + (size_t)t2 * GG + zoff);
            zfa3 = *(const f16x8*)(embW + (size_t)t3 * GG + zoff);
        }
        {
            int nb = 16 + g4 * 4;
            int t0 = toks[(nb + 0) * TT + t];
            int t1 = toks[(nb + 1) * TT + t];
            int t2 = toks[(nb + 2) * TT + t];
            int t3 = toks[(nb + 3) * TT + t];
            zfb0 = *(const f16x8*)(embW + (size_t)t0 * GG + zoff);
            zfb1 = *(const f16x8*)(embW + (size_t)t1 * GG + zoff);
            zfb2 = *(const f16x8*)(embW + (size_t)t2 * GG + zoff);
            zfb3 = *(const f16x8*)(embW + (size_t)t3 * GG + zoff);
        }

        // ---- L0 h-part: h0[cur0] @ Wh0 (JIT B-loads), acc starts at ZERO ----
        f32x4 acc[2][8];
#pragma unroll
        for (int mt = 0; mt < 2; ++mt)
#pragma unroll
            for (int tt = 0; tt < 8; ++tt)
                acc[mt][tt] = (f32x4){0.0f, 0.0f, 0.0f, 0.0f};

        const f16* h0cur = h0s[cur0];
        __builtin_amdgcn_s_setprio(1);
#pragma unroll 2
        for (int kk = 0; kk < 8; ++kk) {
            int k0 = kk * 32 + 8 * g4;
            f16x8 a0 = *(const f16x8*)&h0cur[arow * LDH + k0];
            f16x8 a1 = *(const f16x8*)&h0cur[(arow + 16) * LDH + k0];
            const f16* wkk = wl0 + (size_t)kk * 64 * 64 * 8;
#pragma unroll
            for (int tt = 0; tt < 8; ++tt) {
                int nt = (tt >> 1) * 16 + w * 2 + (tt & 1);
                f16x8 b = *(const f16x8*)(wkk + (size_t)nt * 64 * 8);
                acc[0][tt] = __builtin_amdgcn_mfma_f32_16x16x32_f16(a0, b, acc[0][tt], 0, 0, 0);
                acc[1][tt] = __builtin_amdgcn_mfma_f32_16x16x32_f16(a1, b, acc[1][tt], 0, 0, 0);
            }
        }
        __builtin_amdgcn_s_setprio(0);

        // ---- deferred add: acc += zx (= x@Wx0 + b0); gathers have drained ----
#pragma unroll
        for (int tt = 0; tt < 8; ++tt) {
            acc[0][tt][0] += (float)zfa0[tt];
            acc[0][tt][1] += (float)zfa1[tt];
            acc[0][tt][2] += (float)zfa2[tt];
            acc[0][tt][3] += (float)zfa3[tt];
            acc[1][tt][0] += (float)zfb0[tt];
            acc[1][tt][1] += (float)zfb1[tt];
            acc[1][tt][2] += (float)zfb2[tt];
            acc[1][tt][3] += (float)zfb3[tt];
        }

        // ---- L0 gates -> h0[cur0^1] (no barrier: different buffer) ----
        f16* h0new = h0s[cur0 ^ 1];
#pragma unroll
        for (int mt = 0; mt < 2; ++mt)
#pragma unroll
            for (int sub = 0; sub < 2; ++sub)
#pragma unroll
                for (int r = 0; r < 4; ++r) {
                    int node = mt * 16 + g4 * 4 + r;
                    float i_ = sig_(acc[mt][0 + sub][r]);
                    float f_ = sig_(acc[mt][2 + sub][r]);
                    float g_ = tanh_(acc[mt][4 + sub][r]);
                    float o_ = sig_(acc[mt][6 + sub][r]);
                    int ci = mt * 8 + sub * 4 + r;
                    float c = fmaf(f_, c0[ci], i_ * g_);
                    c0[ci] = c;
                    int u = w * 32 + sub * 16 + arow;
                    h0new[node * LDH + u] = (f16)(o_ * tanh_(c));
                }
        __syncthreads();   // THE barrier: h0new visible to all waves for L1

        // ---- L1: [h0_new | h1_prev] @ [Wx1; Wh1] ----
        f32x4 acc1[2][8];
#pragma unroll
        for (int mt = 0; mt < 2; ++mt)
#pragma unroll
            for (int tt = 0; tt < 8; ++tt)
                acc1[mt][tt] = (f32x4){breg1[tt], breg1[tt], breg1[tt], breg1[tt]};

        const f16* h1cur = h1s[cur1];
        __builtin_amdgcn_s_setprio(1);
#pragma unroll 4
        for (int kk = 0; kk < 16; ++kk) {
            const f16* asrc = (kk < 8) ? (const f16*)h0new : h1cur;
            int k0 = (kk & 7) * 32 + 8 * g4;
            f16x8 a0 = *(const f16x8*)&asrc[arow * LDH + k0];
            f16x8 a1 = *(const f16x8*)&asrc[(arow + 16) * LDH + k0];
            const f16* wkk = wl1 + (size_t)kk * 64 * 64 * 8;
#pragma unroll
            for (int tt = 0; tt < 8; ++tt) {
                int nt = (tt >> 1) * 16 + w * 2 + (tt & 1);
                f16x8 b = *(const f16x8*)(wkk + (size_t)nt * 64 * 8);
                acc1[0][tt] = __builtin_amdgcn_mfma_f32_16x16x32_f16(a0, b, acc1[0][tt], 0, 0, 0);
                acc1[1][tt] = __builtin_amdgcn_mfma_f32_16x16x32_f16(a1, b, acc1[1][tt], 0, 0, 0);
            }
        }
        __builtin_amdgcn_s_setprio(0);

        // ---- L1 gates -> h1[cur1^1] (no barrier: dbuf) ----
#pragma unroll
        for (int mt = 0; mt < 2; ++mt)
#pragma unroll
            for (int sub = 0; sub < 2; ++sub)
#pragma unroll
                for (int r = 0; r < 4; ++r) {
                    int node = mt * 16 + g4 * 4 + r;
                    float i_ = sig_(acc1[mt][0 + sub][r]);
                    float f_ = sig_(acc1[mt][2 + sub][r]);
                    float g_ = tanh_(acc1[mt][4 + sub][r]);
                    float o_ = sig_(acc1[mt][6 + sub][r]);
                    int ci = mt * 8 + sub * 4 + r;
                    float c = fmaf(f_, c1[ci], i_ * g_);
                    c1[ci] = c;
                    int u = w * 32 + sub * 16 + arow;
                    h1s[cur1 ^ 1][node * LDH + u] = (f16)(o_ * tanh_(c));
                }
        cur0 ^= 1;
        cur1 ^= 1;
    }
    __syncthreads();

    for (int i = tid; i < NB2 * HH; i += 512) {
        int n = i >> 8, k = i & 255;
        out[(size_t)(n0 + n) * HH + k] = (float)h1s[cur1][n * LDH + k];
    }
}

// ==================== fallback: round-2 MFMA path ====================
__global__ void convert_embed(const float* __restrict__ e, f16* __restrict__ o, int n8) {
    int i = blockIdx.x * 256 + threadIdx.x;
    if (i >= n8) return;
    size_t p = (size_t)i * 8;
    float4 a = *(const float4*)(e + p);
    float4 b = *(const float4*)(e + p + 4);
    f16x8 v = { (f16)a.x, (f16)a.y, (f16)a.z, (f16)a.w,
                (f16)b.x, (f16)b.y, (f16)b.z, (f16)b.w };
    *(f16x8*)(o + p) = v;
}

#define FB 32
#define FTH 512
#define FLD 264
__device__ __forceinline__ void fb_layer_step(
    const f16 (*bx)[FLD], f16 (*bh)[FLD], const f16* __restrict__ wlayer,
    const float* breg_l, float* c_l, int lane, int w)
{
    f32x4 acc[2][8];
#pragma unroll
    for (int mt = 0; mt < 2; ++mt)
#pragma unroll
        for (int tt = 0; tt < 8; ++tt) {
            float b = breg_l[tt];
            acc[mt][tt] = (f32x4){b, b, b, b};
        }
    const int arow = lane & 15;
    const int koff = 8 * (lane >> 4);
    const f16* wl = wlayer + (size_t)lane * 8;
#pragma unroll 2
    for (int kk = 0; kk < 16; ++kk) {
        int k0 = (kk & 7) * 32 + koff;
        const f16(*src)[FLD] = (kk < 8) ? bx : (const f16(*)[FLD])bh;
        f16x8 a0 = *(const f16x8*)&src[arow][k0];
        f16x8 a1 = *(const f16x8*)&src[arow + 16][k0];
        const f16* wkk = wl + (size_t)kk * 64 * 64 * 8;
#pragma unroll
        for (int tt = 0; tt < 8; ++tt) {
            int nt = (tt >> 1) * 16 + w * 2 + (tt & 1);
            f16x8 b = *(const f16x8*)(wkk + (size_t)nt * 64 * 8);
            acc[0][tt] = __builtin_amdgcn_mfma_f32_16x16x32_f16(a0, b, acc[0][tt], 0, 0, 0);
            acc[1][tt] = __builtin_amdgcn_mfma_f32_16x16x32_f16(a1, b, acc[1][tt], 0, 0, 0);
        }
    }
    __syncthreads();
#pragma unroll
    for (int mt = 0; mt < 2; ++mt)
#pragma unroll
        for (int sub = 0; sub < 2; ++sub) {
            f32x4 iv = acc[mt][0 + sub], fv = acc[mt][2 + sub];
            f32x4 gv = acc[mt][4 + sub], ov = acc[mt][6 + sub];
#pragma unroll
            for (int r = 0; r < 4; ++r) {
                float i_ = sigp_(iv[r]), f_ = sigp_(fv[r]), g_ = tanhp_(gv[r]), o_ = sigp_(ov[r]);
                int ci = mt * 8 + sub * 4 + r;
                float c = fmaf(f_, c_l[ci], i_ * g_);
                c_l[ci] = c;
                int node = mt * 16 + (lane >> 4) * 4 + r;
                int unit = w * 32 + sub * 16 + (lane & 15);
                bh[node][unit] = (f16)(o_ * tanhp_(c));
            }
        }
    __syncthreads();
}

__global__ __launch_bounds__(FTH, 2) void lstm_mfma_fb(
    const int* __restrict__ data, const float* __restrict__ bias,
    const f16* __restrict__ emb, const f16* __restrict__ Wp,
    float* __restrict__ out, int vocab)
{
    __shared__ f16 x_lds[FB][FLD];
    __shared__ f16 h0_lds[FB][FLD];
    __shared__ f16 h1_lds[FB][FLD];
    const int tid = threadIdx.x;
    const int lane = tid & 63;
    const int w = tid >> 6;
    const int n0 = blockIdx.x * FB;
    for (int i = tid; i < FB * FLD; i += FTH) {
        (&h0_lds[0][0])[i] = (f16)0.0f; (&h1_lds[0][0])[i] = (f16)0.0f;
    }
    float breg[2][8];
#pragma unroll
    for (int l = 0; l < 2; ++l)
#pragma unroll
        for (int tt = 0; tt < 8; ++tt) {
            int col = (tt >> 1) * 256 + w * 32 + (tt & 1) * 16 + (lane & 15);
            breg[l][tt] = bias[l * GG + col];
        }
    float cst[2][16];
#pragma unroll
    for (int i = 0; i < 32; ++i) (&cst[0][0])[i] = 0.0f;
    __syncthreads();
    const f16* Wp0 = Wp;
    const f16* Wp1 = Wp + (size_t)16 * 64 * 64 * 8;
    for (int t = 0; t < TT; ++t) {
        {
            int n = tid >> 4;
            int cg = (tid & 15) * 16;
            int row = data[(n0 + n) * TT + t];
            row = min(max(row, 0), vocab - 1);
            const f16* src = emb + (size_t)row * HH + cg;
            *(f16x8*)&x_lds[n][cg] = *(const f16x8*)src;
            *(f16x8*)&x_lds[n][cg + 8] = *(const f16x8*)(src + 8);
        }
        __syncthreads();
        fb_layer_step(x_lds, h0_lds, Wp0, breg[0], cst[0], lane, w);
        fb_layer_step((const f16(*)[FLD])h0_lds, h1_lds, Wp1, breg[1], cst[1], lane, w);
    }
    for (int i = tid; i < FB * HH; i += FTH) {
        int n = i >> 8, k = i & 255;
        out[(size_t)(n0 + n) * HH + k] = (float)h1_lds[n][k];
    }
}

// ==================== launcher ====================
extern "C" void kernel_launch(void* const* d_in, const int* in_sizes, int n_in,
                              void* d_out, int out_size, void* d_ws, size_t ws_size,
                              hipStream_t stream) {
    const int* data = (const int*)d_in[0];
    const float* embed = (const float*)d_in[1];
    const float* Wx = (const float*)d_in[2];
    const float* Wh = (const float*)d_in[3];
    const float* bias = (const float*)d_in[4];
    float* out = (float*)d_out;
    const int vocab = in_sizes[1] / HH;       // 30000
    const int nNodes = in_sizes[0] / TT;      // 4096

    const size_t wp_bytes = (size_t)2 * 16 * 64 * 64 * 8 * 2;   // 2 MB
    const size_t embw_bytes = (size_t)vocab * GG * 2;           // 61.4 MB
    const size_t emb16_bytes = (size_t)vocab * HH * 2;          // 15.4 MB

    if (ws_size >= embw_bytes + wp_bytes) {
        f16* embW = (f16*)d_ws;
        f16* Wp = (f16*)((char*)d_ws + embw_bytes);
        pack_weights<<<dim3(512), dim3(256), 0, stream>>>(Wx, Wh, Wp);
        embw_gemm<<<dim3((vocab + 31) / 32), dim3(512), 0, stream>>>(embed, bias, Wp, embW, vocab);
        lstm_rec2<<<dim3(nNodes / NB2), dim3(512), 0, stream>>>(data, bias, embW, Wp, out);
        return;
    }
    // fallback: fp16 embed table + packed weights (r2 path)
    f16* emb_h = (f16*)d_ws;
    f16* Wp = (f16*)((char*)d_ws + emb16_bytes);
    int n8 = in_sizes[1] / 8;
    convert_embed<<<dim3((n8 + 255) / 256), dim3(256), 0, stream>>>(embed, emb_h, n8);
    pack_weights<<<dim3(512), dim3(256), 0, stream>>>(Wx, Wh, Wp);
    lstm_mfma_fb<<<dim3(nNodes / FB), dim3(FTH), 0, stream>>>(data, bias, emb_h, Wp, out, vocab);
}